// Round 1
// baseline (1037.774 us; speedup 1.0000x reference)
//
#include <hip/hip_runtime.h>

// 2x upsample (upfirdn2d) with separable filter [1,3,3,1]/4 per dim.
// Input: (N*C, 64, 64) f32  ->  Output: (N*C, 127, 127) f32
// Per-dim taps:
//   even out 2r  : 0.25*a[r-1] + 0.75*a[r]   (r-1 may be -1 -> zero)
//   odd  out 2r+1: 0.75*a[r]   + 0.25*a[r+1] (r+1 <= 63 always, since max odd oy=125)

#define IH 64
#define IW 64
#define OH 127
#define OW 127

__global__ __launch_bounds__(128) void up2_kernel(const float* __restrict__ x,
                                                  float* __restrict__ out) {
    const int ox  = threadIdx.x;
    const int oy  = blockIdx.x;
    const int img = blockIdx.y;
    if (ox >= OW) return;

    const float* src = x + (size_t)img * (IH * IW);
    float* dst = out + (size_t)img * (OH * OW) + (size_t)oy * OW + ox;

    const int ry = oy >> 1;
    const int rx = ox >> 1;

    int y0, y1, x0, x1;
    float wy0, wy1, wx0, wx1;
    if (oy & 1) { y0 = ry;     y1 = ry + 1; wy0 = 0.75f; wy1 = 0.25f; }
    else        { y0 = ry - 1; y1 = ry;     wy0 = 0.25f; wy1 = 0.75f; }
    if (ox & 1) { x0 = rx;     x1 = rx + 1; wx0 = 0.75f; wx1 = 0.25f; }
    else        { x0 = rx - 1; x1 = rx;     wx0 = 0.25f; wx1 = 0.75f; }

    float v = 0.f;
    if (y0 >= 0) {
        const float* r0 = src + y0 * IW;
        float h = wx1 * r0[x1];
        if (x0 >= 0) h += wx0 * r0[x0];
        v += wy0 * h;
    }
    {
        const float* r1 = src + y1 * IW;
        float h = wx1 * r1[x1];
        if (x0 >= 0) h += wx0 * r1[x0];
        v += wy1 * h;
    }
    *dst = v;
}

extern "C" void kernel_launch(void* const* d_in, const int* in_sizes, int n_in,
                              void* d_out, int out_size, void* d_ws, size_t ws_size,
                              hipStream_t stream) {
    const float* x = (const float*)d_in[0];
    float* out = (float*)d_out;

    const int NC = in_sizes[0] / (IH * IW);  // 16 * 512 = 8192
    dim3 grid(OH, NC);
    up2_kernel<<<grid, 128, 0, stream>>>(x, out);
}

// Round 4
// 621.573 us; speedup vs baseline: 1.6696x; 1.6696x over previous
//
#include <hip/hip_runtime.h>

// 2x upsample (upfirdn2d) with separable filter [1,3,3,1]/4 per dim.
// Input: (8192, 64, 64) f32  ->  Output: (8192, 127, 127) f32
// Per-dim taps (r = o>>1):
//   even o: 0.25*a[r-1] + 0.75*a[r]
//   odd  o: 0.75*a[r]   + 0.25*a[r+1]
// One block per image. Whole input staged in LDS with a zero-padded top/left
// border so no boundary branches are needed:
//   L[y+1][x+1] = input[y][x], L[0][*] = L[*][0] = 0.

#define IH 64
#define IW 64
#define OH 127
#define OW 127
#define LDS_W 66   // 64 + left pad + 1 trailing pad (bank stagger)
#define LDS_H 65   // 64 + top pad

__global__ __launch_bounds__(256) void up2_kernel(const float* __restrict__ x,
                                                  float* __restrict__ out) {
    __shared__ float L[LDS_H * LDS_W];
    const int tid = threadIdx.x;
    const int img = blockIdx.x;

    // Zero the padded borders: row 0 (LDS_W entries) + col 0 of rows 1..64.
    if (tid < LDS_W) {
        L[tid] = 0.f;                          // top border row
    } else if (tid < LDS_W + (LDS_H - 1)) {
        int y = tid - LDS_W + 1;
        L[y * LDS_W] = 0.f;                    // left border col
    }

    // Stage input: 4096 floats = 1024 float4; 4 per thread.
    const float4* src4 = (const float4*)(x + (size_t)img * (IH * IW));
    #pragma unroll
    for (int i = 0; i < 4; ++i) {
        int v4 = tid + i * 256;                // float4 index 0..1023
        float4 v = src4[v4];
        int iy = v4 >> 4;                      // 16 float4 per input row
        int ix = (v4 & 15) * 4;
        float* p = &L[(iy + 1) * LDS_W + (ix + 1)];
        p[0] = v.x; p[1] = v.y; p[2] = v.z; p[3] = v.w;
    }
    __syncthreads();

    float* dst = out + (size_t)img * (OH * OW);

    #pragma unroll 4
    for (int idx = tid; idx < OH * OW; idx += 256) {
        int oy = idx / OW;                     // magic-mul, const 127
        int ox = idx - oy * OW;
        int sy = oy & 1, sx = ox & 1;
        int y0 = (oy >> 1) + sy;               // padded row of first tap
        int x0 = (ox >> 1) + sx;               // padded col of first tap
        float wy0 = sy ? 0.75f : 0.25f;
        float wy1 = 1.0f - wy0;
        float wx0 = sx ? 0.75f : 0.25f;
        float wx1 = 1.0f - wx0;
        const float* r0 = &L[y0 * LDS_W + x0];
        const float* r1 = r0 + LDS_W;
        float v = wy0 * (wx0 * r0[0] + wx1 * r0[1])
                + wy1 * (wx0 * r1[0] + wx1 * r1[1]);
        dst[idx] = v;
    }
}

extern "C" void kernel_launch(void* const* d_in, const int* in_sizes, int n_in,
                              void* d_out, int out_size, void* d_ws, size_t ws_size,
                              hipStream_t stream) {
    const float* x = (const float*)d_in[0];
    float* out = (float*)d_out;

    const int NC = in_sizes[0] / (IH * IW);    // 16 * 512 = 8192 images
    up2_kernel<<<NC, 256, 0, stream>>>(x, out);
}